// Round 3
// baseline (209.591 us; speedup 1.0000x reference)
//
#include <hip/hip_runtime.h>
#include <hip/hip_bf16.h>

#define B_    128
#define T_    1000
#define D_    1024
#define H_    256
#define TCROP 100
#define CHUNK 20
#define NCH   50            // T_/CHUNK
#define CSKIP 5             // TCROP/CHUNK (exact)

typedef __attribute__((ext_vector_type(8))) short bfrag8;   // 8 x bf16
typedef __attribute__((ext_vector_type(4))) float f32x4;
typedef unsigned long long ull;

__device__ __forceinline__ unsigned short f2bf(float f) {
    union { float f; unsigned int u; } v; v.f = f;
    unsigned int u = v.u;
    u += 0x7FFFu + ((u >> 16) & 1u);   // RNE
    return (unsigned short)(u >> 16);
}
__device__ __forceinline__ float bf2f(unsigned short u) {
    union { unsigned int u; float f; } v; v.u = ((unsigned int)u) << 16;
    return v.f;
}
__device__ __forceinline__ bfrag8 cvt8(float4 f0, float4 f1) {
    bfrag8 v;
    v[0] = (short)f2bf(f0.x); v[1] = (short)f2bf(f0.y);
    v[2] = (short)f2bf(f0.z); v[3] = (short)f2bf(f0.w);
    v[4] = (short)f2bf(f1.x); v[5] = (short)f2bf(f1.y);
    v[6] = (short)f2bf(f1.z); v[7] = (short)f2bf(f1.w);
    return v;
}

// ---------------------------------------------------------------------------
// Kernel 0: W f32 [H][D] -> bf16 (row-major)
// ---------------------------------------------------------------------------
__global__ __launch_bounds__(256) void wconv_kernel(
        const float* __restrict__ W, unsigned short* __restrict__ Wbf) {
    const int i = (blockIdx.x * 256 + threadIdx.x) * 8;
    float4 f0 = *(const float4*)(W + i);
    float4 f1 = *(const float4*)(W + i + 4);
    *(bfrag8*)(Wbf + i) = cvt8(f0, f1);
}

// ---------------------------------------------------------------------------
// Kernel 1: Wx = x(bf16-rounded) . W^T. BM=128, BN=256(=H), BK=64.
// 512 thr = 8 waves (2M x 4N). Double-buffered LDS (96 KB), 1 barrier/K-step,
// counted-wait pipeline: issue A-loads(reg) + B global_load_lds for tile k+1
// BEFORE the MFMA phase of tile k. 16B-chunk XOR swizzle (chunk j at j^(r&7)).
// ---------------------------------------------------------------------------
__global__ __launch_bounds__(512) void gemm_kernel(
        const float* __restrict__ x, const unsigned short* __restrict__ Wbf,
        unsigned short* __restrict__ Wx) {
    __shared__ unsigned short As[2][128 * 64];   // 32 KB
    __shared__ unsigned short Bs[2][256 * 64];   // 64 KB

    const int tid  = threadIdx.x;
    const int lane = tid & 63;
    const int wave = tid >> 6;
    const int wr   = wave >> 2;          // 0..1
    const int wc   = wave & 3;           // 0..3
    const int m0   = blockIdx.x * 128;

    f32x4 acc[4][4];
#pragma unroll
    for (int m = 0; m < 4; ++m)
#pragma unroll
        for (int n = 0; n < 4; ++n) acc[m][n] = (f32x4){0.f, 0.f, 0.f, 0.f};

    const int rr  = lane & 15;
    const int kh  = lane >> 4;           // 0..3
    const int ra0 = tid >> 3;            // 0..63 (and +64)
    const int ja  = tid & 7;
    const int sa  = (ja ^ (ra0 & 7)) * 8;          // A write swizzle (same for ra0+64)
    const float* ap0 = x + (size_t)(m0 + ra0) * D_ + ja * 8;
    const float* ap1 = ap0 + (size_t)64 * D_;

    // ---- prologue: stage tile 0 into buffer 0 ----
#pragma unroll
    for (int q = 0; q < 4; ++q) {
        const int li = q * 512 + tid;
        const int r = li >> 3, j = li & 7;
        const int jj = j ^ (r & 7);
        __builtin_amdgcn_global_load_lds(
            (const __attribute__((address_space(1))) void*)(Wbf + (size_t)r * D_ + jj * 8),
            (__attribute__((address_space(3))) void*)&Bs[0][li * 8], 16, 0, 0);
    }
    {
        float4 f00 = *(const float4*)ap0;
        float4 f01 = *(const float4*)(ap0 + 4);
        float4 f10 = *(const float4*)ap1;
        float4 f11 = *(const float4*)(ap1 + 4);
        *(bfrag8*)&As[0][ra0 * 64 + sa]        = cvt8(f00, f01);
        *(bfrag8*)&As[0][(ra0 + 64) * 64 + sa] = cvt8(f10, f11);
    }
    asm volatile("s_waitcnt vmcnt(0) lgkmcnt(0)" ::: "memory");
    __builtin_amdgcn_sched_barrier(0);
    __builtin_amdgcn_s_barrier();

    for (int it = 0; it < 16; ++it) {
        const int cur = it & 1, nxt = cur ^ 1;
        float4 f00, f01, f10, f11;
        // ---- issue next-tile loads (overlap with MFMA below) ----
        if (it < 15) {
            const int ktn = (it + 1) * 64;
            f00 = *(const float4*)(ap0 + ktn);
            f01 = *(const float4*)(ap0 + ktn + 4);
            f10 = *(const float4*)(ap1 + ktn);
            f11 = *(const float4*)(ap1 + ktn + 4);
#pragma unroll
            for (int q = 0; q < 4; ++q) {
                const int li = q * 512 + tid;
                const int r = li >> 3, j = li & 7;
                const int jj = j ^ (r & 7);
                __builtin_amdgcn_global_load_lds(
                    (const __attribute__((address_space(1))) void*)
                        (Wbf + (size_t)r * D_ + ktn + jj * 8),
                    (__attribute__((address_space(3))) void*)&Bs[nxt][li * 8], 16, 0, 0);
            }
        }
        __builtin_amdgcn_sched_barrier(0);
        // ---- compute tile it from buffer cur ----
#pragma unroll
        for (int kk = 0; kk < 2; ++kk) {
            const int c16 = kk * 4 + kh;
            bfrag8 af[4], bfr[4];
#pragma unroll
            for (int m = 0; m < 4; ++m) {
                const int row = wr * 64 + m * 16 + rr;
                af[m] = *(const bfrag8*)&As[cur][row * 64 + ((c16 ^ (row & 7)) * 8)];
            }
#pragma unroll
            for (int n = 0; n < 4; ++n) {
                const int row = wc * 64 + n * 16 + rr;
                bfr[n] = *(const bfrag8*)&Bs[cur][row * 64 + ((c16 ^ (row & 7)) * 8)];
            }
#pragma unroll
            for (int m = 0; m < 4; ++m)
#pragma unroll
                for (int n = 0; n < 4; ++n)
                    acc[m][n] = __builtin_amdgcn_mfma_f32_16x16x32_bf16(
                        af[m], bfr[n], acc[m][n], 0, 0, 0);
        }
        // ---- A: cvt + ds_write into nxt (compiler waits on f00..f11) ----
        if (it < 15) {
            *(bfrag8*)&As[nxt][ra0 * 64 + sa]        = cvt8(f00, f01);
            *(bfrag8*)&As[nxt][(ra0 + 64) * 64 + sa] = cvt8(f10, f11);
        }
        asm volatile("s_waitcnt vmcnt(0) lgkmcnt(0)" ::: "memory");
        __builtin_amdgcn_sched_barrier(0);
        __builtin_amdgcn_s_barrier();
    }

    // ---- epilogue: bf16 store. C[row=(lane>>4)*4+j][col=lane&15] ----
    const int cl = lane & 15, rg = lane >> 4;
#pragma unroll
    for (int m = 0; m < 4; ++m)
#pragma unroll
        for (int n = 0; n < 4; ++n)
#pragma unroll
            for (int j = 0; j < 4; ++j) {
                const int row = m0 + wr * 64 + m * 16 + rg * 4 + j;
                const int col = wc * 64 + n * 16 + cl;
                Wx[(size_t)row * H_ + col] = f2bf(acc[m][n][j]);
            }
}

// ---------------------------------------------------------------------------
// Scan: chunked linear-recurrence decomposition (CHUNK=20, NCH=50).
// A: per (b,c) zero-seeded chunk-final EMA F. B: carry prefix S.
// C: seeded re-run + softmax accumulation (4-t batched shfl reduce). D: reduce.
// ---------------------------------------------------------------------------
__global__ __launch_bounds__(64) void scanA_kernel(
        const unsigned short* __restrict__ Wx, const float* __restrict__ alpha,
        float* __restrict__ F) {
    const int c = blockIdx.x, b = blockIdx.y;
    const int lane = threadIdx.x;
    const int h = lane * 4;

    const float AMIN = 0.81873075307798182f, AMAX = 0.96078943915232320f;
    float4 al = *(const float4*)(alpha + h);
    float a[4]  = {fminf(fmaxf(al.x, AMIN), AMAX), fminf(fmaxf(al.y, AMIN), AMAX),
                   fminf(fmaxf(al.z, AMIN), AMAX), fminf(fmaxf(al.w, AMIN), AMAX)};
    float om[4] = {1.f - a[0], 1.f - a[1], 1.f - a[2], 1.f - a[3]};

    float ut[4] = {0.f, 0.f, 0.f, 0.f};
    const unsigned short* base = Wx + ((size_t)b * T_ + c * CHUNK) * H_ + h;
#pragma unroll 4
    for (int t = 0; t < CHUNK; ++t) {
        ull wv = *(const ull*)(base + (size_t)t * H_);
        ut[0] = a[0] * ut[0] + om[0] * bf2f((unsigned short)wv);
        ut[1] = a[1] * ut[1] + om[1] * bf2f((unsigned short)(wv >> 16));
        ut[2] = a[2] * ut[2] + om[2] * bf2f((unsigned short)(wv >> 32));
        ut[3] = a[3] * ut[3] + om[3] * bf2f((unsigned short)(wv >> 48));
    }
    float4 o; o.x = ut[0]; o.y = ut[1]; o.z = ut[2]; o.w = ut[3];
    *(float4*)(F + ((size_t)b * NCH + c) * H_ + h) = o;
}

__global__ __launch_bounds__(256) void scanB_kernel(
        const float* __restrict__ F, const float* __restrict__ alpha,
        float* __restrict__ S) {
    const int b = blockIdx.x, h = threadIdx.x;
    const float AMIN = 0.81873075307798182f, AMAX = 0.96078943915232320f;
    const float a = fminf(fmaxf(alpha[h], AMIN), AMAX);
    const float aL = powf(a, (float)CHUNK);
    float s = 0.f;
    for (int c = 0; c < NCH; ++c) {
        S[((size_t)b * NCH + c) * H_ + h] = s;
        s = aL * s + F[((size_t)b * NCH + c) * H_ + h];
    }
}

__global__ __launch_bounds__(64) void scanC_kernel(
        const unsigned short* __restrict__ Wx, const float* __restrict__ alpha,
        const float* __restrict__ S, float* __restrict__ P) {
    const int c = blockIdx.x + CSKIP;     // 5..49
    const int b = blockIdx.y;
    const int lane = threadIdx.x;
    const int h = lane * 4;

    const float AMIN = 0.81873075307798182f, AMAX = 0.96078943915232320f;
    float4 al = *(const float4*)(alpha + h);
    float a[4]  = {fminf(fmaxf(al.x, AMIN), AMAX), fminf(fmaxf(al.y, AMIN), AMAX),
                   fminf(fmaxf(al.z, AMIN), AMAX), fminf(fmaxf(al.w, AMIN), AMAX)};
    float om[4] = {1.f - a[0], 1.f - a[1], 1.f - a[2], 1.f - a[3]};

    float4 s0 = *(const float4*)(S + ((size_t)b * NCH + c) * H_ + h);
    float ut[4]   = {s0.x, s0.y, s0.z, s0.w};
    float acc4[4] = {0.f, 0.f, 0.f, 0.f};

    const unsigned short* base = Wx + ((size_t)b * T_ + c * CHUNK) * H_ + h;
#pragma unroll
    for (int tb = 0; tb < CHUNK; tb += 4) {
        float e[4][4], sl[4];
#pragma unroll
        for (int q = 0; q < 4; ++q) {
            ull wv = *(const ull*)(base + (size_t)(tb + q) * H_);
            ut[0] = a[0] * ut[0] + om[0] * bf2f((unsigned short)wv);
            ut[1] = a[1] * ut[1] + om[1] * bf2f((unsigned short)(wv >> 16));
            ut[2] = a[2] * ut[2] + om[2] * bf2f((unsigned short)(wv >> 32));
            ut[3] = a[3] * ut[3] + om[3] * bf2f((unsigned short)(wv >> 48));
            e[q][0] = __expf(ut[0]);   // |ut| small: overflow impossible, skip max-sub
            e[q][1] = __expf(ut[1]);
            e[q][2] = __expf(ut[2]);
            e[q][3] = __expf(ut[3]);
            sl[q] = (e[q][0] + e[q][1]) + (e[q][2] + e[q][3]);
        }
        // 4 independent butterfly chains pipeline in the DS unit
#pragma unroll
        for (int d = 1; d < 64; d <<= 1) {
            sl[0] += __shfl_xor(sl[0], d);
            sl[1] += __shfl_xor(sl[1], d);
            sl[2] += __shfl_xor(sl[2], d);
            sl[3] += __shfl_xor(sl[3], d);
        }
#pragma unroll
        for (int q = 0; q < 4; ++q) {
            const float rcp = 1.0f / sl[q];
            acc4[0] += e[q][0] * rcp;
            acc4[1] += e[q][1] * rcp;
            acc4[2] += e[q][2] * rcp;
            acc4[3] += e[q][3] * rcp;
        }
    }
    float4 o; o.x = acc4[0]; o.y = acc4[1]; o.z = acc4[2]; o.w = acc4[3];
    *(float4*)(P + ((size_t)b * NCH + c) * H_ + h) = o;
}

__global__ __launch_bounds__(256) void scanD_kernel(
        const float* __restrict__ P, float* __restrict__ out) {
    const int b = blockIdx.x, h = threadIdx.x;
    float s = 0.f;
    for (int c = CSKIP; c < NCH; ++c) s += P[((size_t)b * NCH + c) * H_ + h];
    out[(size_t)b * H_ + h] = s;
}

extern "C" void kernel_launch(void* const* d_in, const int* in_sizes, int n_in,
                              void* d_out, int out_size, void* d_ws, size_t ws_size,
                              hipStream_t stream) {
    const float* x     = (const float*)d_in[0];   // [B,T,D]
    const float* W     = (const float*)d_in[1];   // [H,D]
    const float* alpha = (const float*)d_in[2];   // [H]
    float* out = (float*)d_out;                   // [B,H]

    char* ws = (char*)d_ws;                       // ws ~2 GB (per poison fill)
    unsigned short* Wbf = (unsigned short*)ws;                    // 512 KB
    unsigned short* Wx  = (unsigned short*)(ws + ((size_t)1 << 20));   // 65.5 MB
    float* F = (float*)(ws + ((size_t)70 << 20));                 // 6.55 MB
    float* S = (float*)(ws + ((size_t)80 << 20));                 // 6.55 MB
    float* P = (float*)(ws + ((size_t)90 << 20));                 // 6.55 MB

    wconv_kernel<<<128, 256, 0, stream>>>(W, Wbf);
    gemm_kernel<<<(B_ * T_) / 128, 512, 0, stream>>>(x, Wbf, Wx);
    scanA_kernel<<<dim3(NCH, B_), 64, 0, stream>>>(Wx, alpha, F);
    scanB_kernel<<<B_, H_, 0, stream>>>(F, alpha, S);
    scanC_kernel<<<dim3(NCH - CSKIP, B_), 64, 0, stream>>>(Wx, alpha, S, P);
    scanD_kernel<<<B_, H_, 0, stream>>>(P, out);
}

// Round 4
// 205.333 us; speedup vs baseline: 1.0207x; 1.0207x over previous
//
#include <hip/hip_runtime.h>
#include <hip/hip_bf16.h>

#define B_    128
#define T_    1000
#define D_    1024
#define H_    256
#define TCROP 100
#define CHK   125          // t-rows per block (M-tile usable rows)
#define NC    8            // chunks per b (T_/CHK)
#define NOUT  900          // T_ - TCROP

typedef __attribute__((ext_vector_type(8))) short bfrag8;   // 8 x bf16
typedef __attribute__((ext_vector_type(4))) float f32x4;
typedef unsigned long long ull;

__device__ __forceinline__ unsigned short f2bf(float f) {
    union { float f; unsigned int u; } v; v.f = f;
    unsigned int u = v.u;
    u += 0x7FFFu + ((u >> 16) & 1u);   // RNE
    return (unsigned short)(u >> 16);
}
__device__ __forceinline__ float bf2f(unsigned short u) {
    union { unsigned int u; float f; } v; v.u = ((unsigned int)u) << 16;
    return v.f;
}
__device__ __forceinline__ bfrag8 cvt8(float4 f0, float4 f1) {
    bfrag8 v;
    v[0] = (short)f2bf(f0.x); v[1] = (short)f2bf(f0.y);
    v[2] = (short)f2bf(f0.z); v[3] = (short)f2bf(f0.w);
    v[4] = (short)f2bf(f1.x); v[5] = (short)f2bf(f1.y);
    v[6] = (short)f2bf(f1.z); v[7] = (short)f2bf(f1.w);
    return v;
}

// ---------------------------------------------------------------------------
// Kernel 0: W f32 [H][D] -> bf16 (row-major)
// ---------------------------------------------------------------------------
__global__ __launch_bounds__(256) void wconv_kernel(
        const float* __restrict__ W, unsigned short* __restrict__ Wbf) {
    const int i = (blockIdx.x * 256 + threadIdx.x) * 8;
    float4 f0 = *(const float4*)(W + i);
    float4 f1 = *(const float4*)(W + i + 4);
    *(bfrag8*)(Wbf + i) = cvt8(f0, f1);
}

// ---------------------------------------------------------------------------
// Kernel 1: block (c,b) computes Wx tile [125 t][256 h] via bf16 MFMA
// (round-2 proven core: single-buffer LDS, 2 barriers/K-step, + A-reg
// prefetch during MFMA), then writes acc -> LDS(bf16) and runs the
// chunk-local EMA in-block. Outputs: utl (bf16, t>=100) and F (chunk finals).
// LDS: union of staging (48 KB) and C-tile (64 KB) = 64 KB -> 2 blocks/CU.
// ---------------------------------------------------------------------------
__global__ __launch_bounds__(512) void gemm_ema_kernel(
        const float* __restrict__ x, const unsigned short* __restrict__ Wbf,
        const float* __restrict__ alpha,
        unsigned short* __restrict__ utl, float* __restrict__ F) {
    __shared__ unsigned short smem[128 * 256];        // 64 KB
    unsigned short* As = smem;                        // [128][64] bf16
    unsigned short* Bs = smem + 128 * 64;             // [256][64] bf16

    const int tid  = threadIdx.x;
    const int lane = tid & 63;
    const int wave = tid >> 6;
    const int wr   = wave >> 2;          // 0..1
    const int wc   = wave & 3;           // 0..3
    const int c    = blockIdx.x;         // chunk 0..7
    const int b    = blockIdx.y;
    const int m0   = b * T_ + c * CHK;   // global row base (all rows same b)

    f32x4 acc[4][4];
#pragma unroll
    for (int m = 0; m < 4; ++m)
#pragma unroll
        for (int n = 0; n < 4; ++n) acc[m][n] = (f32x4){0.f, 0.f, 0.f, 0.f};

    const int rr  = lane & 15;
    const int kh  = lane >> 4;           // 0..3
    const int ra0 = tid >> 3;            // 0..63
    const int ja  = tid & 7;
    const int sa  = (ja ^ (ra0 & 7)) * 8;
    const int rA1 = (ra0 + 64 < CHK) ? (ra0 + 64) : (CHK - 1);  // clamp pad rows
    const float* ap0 = x + (size_t)(m0 + ra0) * D_ + ja * 8;
    const float* ap1 = x + (size_t)(m0 + rA1) * D_ + ja * 8;

    // prefetch A regs for K-step 0
    float4 p00 = *(const float4*)ap0;
    float4 p01 = *(const float4*)(ap0 + 4);
    float4 p10 = *(const float4*)ap1;
    float4 p11 = *(const float4*)(ap1 + 4);

    for (int it = 0; it < 16; ++it) {
        const int kt = it * 64;
        // ---- B stage: global_load_lds, source pre-swizzled ----
#pragma unroll
        for (int q = 0; q < 4; ++q) {
            const int li = q * 512 + tid;
            const int r = li >> 3, j = li & 7;
            const int jj = j ^ (r & 7);
            __builtin_amdgcn_global_load_lds(
                (const __attribute__((address_space(1))) void*)
                    (Wbf + (size_t)r * D_ + kt + jj * 8),
                (__attribute__((address_space(3))) void*)&Bs[li * 8], 16, 0, 0);
        }
        // ---- A stage: cvt prefetched regs, swizzled ds_write ----
        *(bfrag8*)&As[ra0 * 64 + sa]        = cvt8(p00, p01);
        *(bfrag8*)&As[(ra0 + 64) * 64 + sa] = cvt8(p10, p11);
        __syncthreads();
        // ---- issue next-tile A loads (land during MFMA phase) ----
        if (it < 15) {
            const int ktn = kt + 64;
            p00 = *(const float4*)(ap0 + ktn);
            p01 = *(const float4*)(ap0 + ktn + 4);
            p10 = *(const float4*)(ap1 + ktn);
            p11 = *(const float4*)(ap1 + ktn + 4);
        }
        // ---- MFMA ----
#pragma unroll
        for (int kk = 0; kk < 2; ++kk) {
            const int c16 = kk * 4 + kh;
            bfrag8 af[4], bfr[4];
#pragma unroll
            for (int m = 0; m < 4; ++m) {
                const int row = wr * 64 + m * 16 + rr;
                af[m] = *(const bfrag8*)&As[row * 64 + ((c16 ^ (row & 7)) * 8)];
            }
#pragma unroll
            for (int n = 0; n < 4; ++n) {
                const int row = wc * 64 + n * 16 + rr;
                bfr[n] = *(const bfrag8*)&Bs[row * 64 + ((c16 ^ (row & 7)) * 8)];
            }
#pragma unroll
            for (int m = 0; m < 4; ++m)
#pragma unroll
                for (int n = 0; n < 4; ++n)
                    acc[m][n] = __builtin_amdgcn_mfma_f32_16x16x32_bf16(
                        af[m], bfr[n], acc[m][n], 0, 0, 0);
        }
        __syncthreads();
    }

    // ---- acc -> LDS C tile (bf16, col-swizzled by row-group to avoid
    //      4-way bank conflicts: col' = (col + rg*16) & 255) ----
    const int cl = lane & 15, rg = lane >> 4;
#pragma unroll
    for (int m = 0; m < 4; ++m)
#pragma unroll
        for (int n = 0; n < 4; ++n)
#pragma unroll
            for (int j = 0; j < 4; ++j) {
                const int row = wr * 64 + m * 16 + rg * 4 + j;
                const int col = (wc * 64 + n * 16 + cl + rg * 16) & 255;
                smem[row * 256 + col] = f2bf(acc[m][n][j]);
            }
    __syncthreads();

    // ---- chunk-local EMA over t (serial, in LDS); emit utl + F ----
    if (tid < H_) {
        const int h = tid;
        const float AMIN = 0.81873075307798182f, AMAX = 0.96078943915232320f;
        const float a  = fminf(fmaxf(alpha[h], AMIN), AMAX);
        const float om = 1.0f - a;
        float ut = 0.f;
        const int t0 = c * CHK;
        for (int r = 0; r < CHK; ++r) {
            const int col = (h + ((r >> 2) & 3) * 16) & 255;
            ut = a * ut + om * bf2f(smem[r * 256 + col]);
            const int t = t0 + r;
            if (t >= TCROP)
                utl[((size_t)b * NOUT + (t - TCROP)) * H_ + h] = f2bf(ut);
        }
        F[((size_t)b * NC + c) * H_ + h] = ut;
    }
}

// ---------------------------------------------------------------------------
// Kernel 2: seeded softmax accumulation. Block (c,b), 1 wave, lane owns 4 h.
// S_c chained from F (<=7 steps); ut(t) = utl(t) + a^(r+1)*S_c -> all t
// independent (no recurrence). 5-t batches: independent loads/exp/shfl-chains.
// ---------------------------------------------------------------------------
__global__ __launch_bounds__(64) void scanC_kernel(
        const unsigned short* __restrict__ utl, const float* __restrict__ alpha,
        const float* __restrict__ F, float* __restrict__ P) {
    const int c = blockIdx.x, b = blockIdx.y;
    const int lane = threadIdx.x;
    const int h4 = lane * 4;

    const float AMIN = 0.81873075307798182f, AMAX = 0.96078943915232320f;
    float4 al = *(const float4*)(alpha + h4);
    float a[4] = {fminf(fmaxf(al.x, AMIN), AMAX), fminf(fmaxf(al.y, AMIN), AMAX),
                  fminf(fmaxf(al.z, AMIN), AMAX), fminf(fmaxf(al.w, AMIN), AMAX)};

    float S[4] = {0.f, 0.f, 0.f, 0.f};
    if (c > 0) {
        float aL[4] = {__powf(a[0], (float)CHK), __powf(a[1], (float)CHK),
                       __powf(a[2], (float)CHK), __powf(a[3], (float)CHK)};
        for (int j = 0; j < c; ++j) {
            float4 f = *(const float4*)(F + ((size_t)b * NC + j) * H_ + h4);
            S[0] = aL[0] * S[0] + f.x;
            S[1] = aL[1] * S[1] + f.y;
            S[2] = aL[2] * S[2] + f.z;
            S[3] = aL[3] * S[3] + f.w;
        }
    }

    const int nt = (c == 0) ? (CHK - TCROP) : CHK;          // 25 or 125
    const size_t ti0 = (size_t)b * NOUT + (c == 0 ? 0 : c * CHK - TCROP);
    const unsigned short* base = utl + ti0 * H_ + h4;

    float d[4]    = {1.f, 1.f, 1.f, 1.f};
    float acc4[4] = {0.f, 0.f, 0.f, 0.f};

    for (int bb = 0; bb < nt; bb += 5) {
        float e[5][4], sl[5];
#pragma unroll
        for (int q = 0; q < 5; ++q) {
            ull wv = *(const ull*)(base + (size_t)(bb + q) * H_);
            d[0] *= a[0]; d[1] *= a[1]; d[2] *= a[2]; d[3] *= a[3];
            float u0 = bf2f((unsigned short)wv)         + d[0] * S[0];
            float u1 = bf2f((unsigned short)(wv >> 16)) + d[1] * S[1];
            float u2 = bf2f((unsigned short)(wv >> 32)) + d[2] * S[2];
            float u3 = bf2f((unsigned short)(wv >> 48)) + d[3] * S[3];
            e[q][0] = __expf(u0);   // |ut| small: overflow impossible, skip max-sub
            e[q][1] = __expf(u1);
            e[q][2] = __expf(u2);
            e[q][3] = __expf(u3);
            sl[q] = (e[q][0] + e[q][1]) + (e[q][2] + e[q][3]);
        }
#pragma unroll
        for (int dd = 1; dd < 64; dd <<= 1) {
            sl[0] += __shfl_xor(sl[0], dd);
            sl[1] += __shfl_xor(sl[1], dd);
            sl[2] += __shfl_xor(sl[2], dd);
            sl[3] += __shfl_xor(sl[3], dd);
            sl[4] += __shfl_xor(sl[4], dd);
        }
#pragma unroll
        for (int q = 0; q < 5; ++q) {
            const float rcp = 1.0f / sl[q];
            acc4[0] += e[q][0] * rcp;
            acc4[1] += e[q][1] * rcp;
            acc4[2] += e[q][2] * rcp;
            acc4[3] += e[q][3] * rcp;
        }
    }
    float4 o; o.x = acc4[0]; o.y = acc4[1]; o.z = acc4[2]; o.w = acc4[3];
    *(float4*)(P + ((size_t)b * NC + c) * H_ + h4) = o;
}

// ---------------------------------------------------------------------------
// Kernel 3: reduce chunk partials
// ---------------------------------------------------------------------------
__global__ __launch_bounds__(256) void scanD_kernel(
        const float* __restrict__ P, float* __restrict__ out) {
    const int b = blockIdx.x, h = threadIdx.x;
    float s = 0.f;
#pragma unroll
    for (int c = 0; c < NC; ++c) s += P[((size_t)b * NC + c) * H_ + h];
    out[(size_t)b * H_ + h] = s;
}

extern "C" void kernel_launch(void* const* d_in, const int* in_sizes, int n_in,
                              void* d_out, int out_size, void* d_ws, size_t ws_size,
                              hipStream_t stream) {
    const float* x     = (const float*)d_in[0];   // [B,T,D]
    const float* W     = (const float*)d_in[1];   // [H,D]
    const float* alpha = (const float*)d_in[2];   // [H]
    float* out = (float*)d_out;                   // [B,H]

    char* ws = (char*)d_ws;
    unsigned short* Wbf = (unsigned short*)ws;                        // 512 KB
    unsigned short* utl = (unsigned short*)(ws + ((size_t)1 << 20));  // 59 MB
    float* F = (float*)(ws + ((size_t)64 << 20));                     // 1 MB
    float* P = (float*)(ws + ((size_t)66 << 20));                     // 1 MB

    wconv_kernel<<<128, 256, 0, stream>>>(W, Wbf);
    gemm_ema_kernel<<<dim3(NC, B_), 512, 0, stream>>>(x, Wbf, alpha, utl, F);
    scanC_kernel<<<dim3(NC, B_), 64, 0, stream>>>(utl, alpha, F, P);
    scanD_kernel<<<B_, 256, 0, stream>>>(P, out);
}

// Round 5
// 194.895 us; speedup vs baseline: 1.0754x; 1.0536x over previous
//
#include <hip/hip_runtime.h>
#include <hip/hip_bf16.h>

#define B_    128
#define T_    1000
#define D_    1024
#define H_    256
#define TCROP 100
#define CHUNK 25
#define NCHK  40           // T_/CHUNK
#define CSKIP 4            // TCROP/CHUNK exact
#define NOUTC 36           // NCHK - CSKIP

typedef __attribute__((ext_vector_type(8))) short bfrag8;   // 8 x bf16
typedef __attribute__((ext_vector_type(4))) float f32x4;
typedef unsigned long long ull;

__device__ __forceinline__ unsigned short f2bf(float f) {
    union { float f; unsigned int u; } v; v.f = f;
    unsigned int u = v.u;
    u += 0x7FFFu + ((u >> 16) & 1u);
    return (unsigned short)(u >> 16);
}
__device__ __forceinline__ float bf2f(unsigned short u) {
    union { unsigned int u; float f; } v; v.u = ((unsigned int)u) << 16;
    return v.f;
}
// pack two f32 -> (bf16(hi)<<16)|bf16(lo), round-half-away: 2 adds + 1 v_perm
__device__ __forceinline__ unsigned int pack2(float lo, float hi) {
    union { float f; unsigned int u; } a, b; a.f = lo; b.f = hi;
    return __builtin_amdgcn_perm(b.u + 0x8000u, a.u + 0x8000u, 0x07060302u);
}
__device__ __forceinline__ bfrag8 cvt8(float4 f0, float4 f1) {
    union { bfrag8 v; unsigned int u[4]; } r;
    r.u[0] = pack2(f0.x, f0.y);
    r.u[1] = pack2(f0.z, f0.w);
    r.u[2] = pack2(f1.x, f1.y);
    r.u[3] = pack2(f1.z, f1.w);
    return r.v;
}

// ---------------------------------------------------------------------------
// Kernel 0: W f32 [H][D] -> bf16 (row-major)
// ---------------------------------------------------------------------------
__global__ __launch_bounds__(256) void wconv_kernel(
        const float* __restrict__ W, unsigned short* __restrict__ Wbf) {
    const int i = (blockIdx.x * 256 + threadIdx.x) * 8;
    float4 f0 = *(const float4*)(W + i);
    float4 f1 = *(const float4*)(W + i + 4);
    *(bfrag8*)(Wbf + i) = cvt8(f0, f1);
}

// ---------------------------------------------------------------------------
// Kernel 1: Wx = x . W^T  (bf16 MFMA, bf16 out). BM=128, BN=256(=H), BK=64.
// Round-2 proven core: single-buffer 48 KB LDS, 2 barriers/K-step.
// launch_bounds(512,4) pins VGPR<=128 -> 2 blocks/CU. A prefetched into regs
// AFTER the first barrier (in flight during MFMA phase).
// ---------------------------------------------------------------------------
__global__ __launch_bounds__(512, 4) void gemm_kernel(
        const float* __restrict__ x, const unsigned short* __restrict__ Wbf,
        unsigned short* __restrict__ Wx) {
    __shared__ unsigned short As[128 * 64];   // 16 KB
    __shared__ unsigned short Bs[256 * 64];   // 32 KB

    const int tid  = threadIdx.x;
    const int lane = tid & 63;
    const int wave = tid >> 6;
    const int wr   = wave >> 2;
    const int wc   = wave & 3;
    const int m0   = blockIdx.x * 128;

    f32x4 acc[4][4];
#pragma unroll
    for (int m = 0; m < 4; ++m)
#pragma unroll
        for (int n = 0; n < 4; ++n) acc[m][n] = (f32x4){0.f, 0.f, 0.f, 0.f};

    const int rr  = lane & 15;
    const int kh  = lane >> 4;
    const int ra0 = tid >> 3;
    const int ja  = tid & 7;
    const int sa  = (ja ^ (ra0 & 7)) * 8;
    const float* ap0 = x + (size_t)(m0 + ra0) * D_ + ja * 8;
    const float* ap1 = ap0 + (size_t)64 * D_;

    // prefetch A for K-step 0
    float4 p00 = *(const float4*)ap0;
    float4 p01 = *(const float4*)(ap0 + 4);
    float4 p10 = *(const float4*)ap1;
    float4 p11 = *(const float4*)(ap1 + 4);

    for (int it = 0; it < 16; ++it) {
        const int kt = it * 64;
        // ---- B stage: global_load_lds, source pre-swizzled ----
#pragma unroll
        for (int q = 0; q < 4; ++q) {
            const int li = q * 512 + tid;
            const int r = li >> 3, j = li & 7;
            const int jj = j ^ (r & 7);
            __builtin_amdgcn_global_load_lds(
                (const __attribute__((address_space(1))) void*)
                    (Wbf + (size_t)r * D_ + kt + jj * 8),
                (__attribute__((address_space(3))) void*)&Bs[li * 8], 16, 0, 0);
        }
        // ---- A stage: cvt prefetched regs, swizzled ds_write ----
        *(bfrag8*)&As[ra0 * 64 + sa]        = cvt8(p00, p01);
        *(bfrag8*)&As[(ra0 + 64) * 64 + sa] = cvt8(p10, p11);
        __syncthreads();
        // ---- issue next-step A loads; they land during the MFMA phase ----
        if (it < 15) {
            const int ktn = kt + 64;
            p00 = *(const float4*)(ap0 + ktn);
            p01 = *(const float4*)(ap0 + ktn + 4);
            p10 = *(const float4*)(ap1 + ktn);
            p11 = *(const float4*)(ap1 + ktn + 4);
        }
        // ---- MFMA ----
#pragma unroll
        for (int kk = 0; kk < 2; ++kk) {
            const int c16 = kk * 4 + kh;
            bfrag8 af[4], bfr[4];
#pragma unroll
            for (int m = 0; m < 4; ++m) {
                const int row = wr * 64 + m * 16 + rr;
                af[m] = *(const bfrag8*)&As[row * 64 + ((c16 ^ (row & 7)) * 8)];
            }
#pragma unroll
            for (int n = 0; n < 4; ++n) {
                const int row = wc * 64 + n * 16 + rr;
                bfr[n] = *(const bfrag8*)&Bs[row * 64 + ((c16 ^ (row & 7)) * 8)];
            }
#pragma unroll
            for (int m = 0; m < 4; ++m)
#pragma unroll
                for (int n = 0; n < 4; ++n)
                    acc[m][n] = __builtin_amdgcn_mfma_f32_16x16x32_bf16(
                        af[m], bfr[n], acc[m][n], 0, 0, 0);
        }
        __syncthreads();
    }

    const int cl = lane & 15, rg = lane >> 4;
#pragma unroll
    for (int m = 0; m < 4; ++m)
#pragma unroll
        for (int n = 0; n < 4; ++n)
#pragma unroll
            for (int j = 0; j < 4; ++j) {
                const int row = m0 + wr * 64 + m * 16 + rg * 4 + j;
                const int col = wc * 64 + n * 16 + cl;
                Wx[(size_t)row * H_ + col] = f2bf(acc[m][n][j]);
            }
}

// ---------------------------------------------------------------------------
// Kernel 2 (scanA): chunk-local zero-seeded EMA finals F. 4 waves/block,
// wave w owns chunk c = bx*4+w of batch b. Lane owns 4 h.
// ---------------------------------------------------------------------------
__global__ __launch_bounds__(256) void scanA_kernel(
        const unsigned short* __restrict__ Wx, const float* __restrict__ alpha,
        float* __restrict__ F) {
    const int wave = threadIdx.x >> 6;
    const int lane = threadIdx.x & 63;
    const int c = blockIdx.x * 4 + wave;      // 0..39
    const int b = blockIdx.y;
    const int h4 = lane * 4;

    const float AMIN = 0.81873075307798182f, AMAX = 0.96078943915232320f;
    float4 al = *(const float4*)(alpha + h4);
    float a[4]  = {fminf(fmaxf(al.x, AMIN), AMAX), fminf(fmaxf(al.y, AMIN), AMAX),
                   fminf(fmaxf(al.z, AMIN), AMAX), fminf(fmaxf(al.w, AMIN), AMAX)};
    float om[4] = {1.f - a[0], 1.f - a[1], 1.f - a[2], 1.f - a[3]};

    float ut[4] = {0.f, 0.f, 0.f, 0.f};
    const unsigned short* base = Wx + ((size_t)b * T_ + c * CHUNK) * H_ + h4;
#pragma unroll 5
    for (int t = 0; t < CHUNK; ++t) {
        ull wv = *(const ull*)(base + (size_t)t * H_);
        ut[0] = a[0] * ut[0] + om[0] * bf2f((unsigned short)wv);
        ut[1] = a[1] * ut[1] + om[1] * bf2f((unsigned short)(wv >> 16));
        ut[2] = a[2] * ut[2] + om[2] * bf2f((unsigned short)(wv >> 32));
        ut[3] = a[3] * ut[3] + om[3] * bf2f((unsigned short)(wv >> 48));
    }
    float4 o; o.x = ut[0]; o.y = ut[1]; o.z = ut[2]; o.w = ut[3];
    *(float4*)(F + ((size_t)b * NCHK + c) * H_ + h4) = o;
}

// ---------------------------------------------------------------------------
// Kernel 3 (scanC): seed-chain from F (a^25 powers, F is L2-hot), then
// seeded softmax accumulation over the chunk. Wave w owns chunk c=4+bx*4+w.
// 5-t batches -> 5 independent shfl-reduction trees.
// ---------------------------------------------------------------------------
__global__ __launch_bounds__(256) void scanC_kernel(
        const unsigned short* __restrict__ Wx, const float* __restrict__ alpha,
        const float* __restrict__ F, float* __restrict__ P) {
    const int wave = threadIdx.x >> 6;
    const int lane = threadIdx.x & 63;
    const int c = CSKIP + blockIdx.x * 4 + wave;   // 4..39
    const int b = blockIdx.y;
    const int h4 = lane * 4;

    const float AMIN = 0.81873075307798182f, AMAX = 0.96078943915232320f;
    float4 al = *(const float4*)(alpha + h4);
    float a[4]  = {fminf(fmaxf(al.x, AMIN), AMAX), fminf(fmaxf(al.y, AMIN), AMAX),
                   fminf(fmaxf(al.z, AMIN), AMAX), fminf(fmaxf(al.w, AMIN), AMAX)};
    float om[4] = {1.f - a[0], 1.f - a[1], 1.f - a[2], 1.f - a[3]};

    // carry chain: S = ut at chunk start
    float aL[4] = {__powf(a[0], (float)CHUNK), __powf(a[1], (float)CHUNK),
                   __powf(a[2], (float)CHUNK), __powf(a[3], (float)CHUNK)};
    float S[4] = {0.f, 0.f, 0.f, 0.f};
    for (int j = 0; j < c; ++j) {
        float4 f = *(const float4*)(F + ((size_t)b * NCHK + j) * H_ + h4);
        S[0] = aL[0] * S[0] + f.x;
        S[1] = aL[1] * S[1] + f.y;
        S[2] = aL[2] * S[2] + f.z;
        S[3] = aL[3] * S[3] + f.w;
    }

    float ut[4]   = {S[0], S[1], S[2], S[3]};
    float acc4[4] = {0.f, 0.f, 0.f, 0.f};
    const unsigned short* base = Wx + ((size_t)b * T_ + c * CHUNK) * H_ + h4;

#pragma unroll
    for (int bb = 0; bb < CHUNK; bb += 5) {
        float e[5][4], sl[5];
#pragma unroll
        for (int q = 0; q < 5; ++q) {
            ull wv = *(const ull*)(base + (size_t)(bb + q) * H_);
            ut[0] = a[0] * ut[0] + om[0] * bf2f((unsigned short)wv);
            ut[1] = a[1] * ut[1] + om[1] * bf2f((unsigned short)(wv >> 16));
            ut[2] = a[2] * ut[2] + om[2] * bf2f((unsigned short)(wv >> 32));
            ut[3] = a[3] * ut[3] + om[3] * bf2f((unsigned short)(wv >> 48));
            e[q][0] = __expf(ut[0]);   // |ut| small: no overflow, skip max-sub
            e[q][1] = __expf(ut[1]);
            e[q][2] = __expf(ut[2]);
            e[q][3] = __expf(ut[3]);
            sl[q] = (e[q][0] + e[q][1]) + (e[q][2] + e[q][3]);
        }
#pragma unroll
        for (int dd = 1; dd < 64; dd <<= 1) {
            sl[0] += __shfl_xor(sl[0], dd);
            sl[1] += __shfl_xor(sl[1], dd);
            sl[2] += __shfl_xor(sl[2], dd);
            sl[3] += __shfl_xor(sl[3], dd);
            sl[4] += __shfl_xor(sl[4], dd);
        }
#pragma unroll
        for (int q = 0; q < 5; ++q) {
            const float rcp = 1.0f / sl[q];
            acc4[0] += e[q][0] * rcp;
            acc4[1] += e[q][1] * rcp;
            acc4[2] += e[q][2] * rcp;
            acc4[3] += e[q][3] * rcp;
        }
    }
    float4 o; o.x = acc4[0]; o.y = acc4[1]; o.z = acc4[2]; o.w = acc4[3];
    *(float4*)(P + ((size_t)b * NOUTC + (c - CSKIP)) * H_ + h4) = o;
}

// ---------------------------------------------------------------------------
// Kernel 4: reduce chunk partials
// ---------------------------------------------------------------------------
__global__ __launch_bounds__(256) void scanD_kernel(
        const float* __restrict__ P, float* __restrict__ out) {
    const int b = blockIdx.x, h = threadIdx.x;
    float s = 0.f;
#pragma unroll 4
    for (int k = 0; k < NOUTC; ++k) s += P[((size_t)b * NOUTC + k) * H_ + h];
    out[(size_t)b * H_ + h] = s;
}

extern "C" void kernel_launch(void* const* d_in, const int* in_sizes, int n_in,
                              void* d_out, int out_size, void* d_ws, size_t ws_size,
                              hipStream_t stream) {
    const float* x     = (const float*)d_in[0];   // [B,T,D]
    const float* W     = (const float*)d_in[1];   // [H,D]
    const float* alpha = (const float*)d_in[2];   // [H]
    float* out = (float*)d_out;                   // [B,H]

    char* ws = (char*)d_ws;
    unsigned short* Wbf = (unsigned short*)ws;                        // 512 KB
    unsigned short* Wx  = (unsigned short*)(ws + ((size_t)1 << 20));  // 65.5 MB
    float* F = (float*)(ws + ((size_t)70 << 20));                     // 5.2 MB
    float* P = (float*)(ws + ((size_t)80 << 20));                     // 4.7 MB

    wconv_kernel<<<128, 256, 0, stream>>>(W, Wbf);
    gemm_kernel<<<(B_ * T_) / 128, 512, 0, stream>>>(x, Wbf, Wx);
    scanA_kernel<<<dim3(NCHK / 4, B_), 256, 0, stream>>>(Wx, alpha, F);
    scanC_kernel<<<dim3(NOUTC / 4, B_), 256, 0, stream>>>(Wx, alpha, F, P);
    scanD_kernel<<<B_, 256, 0, stream>>>(P, out);
}

// Round 6
// 188.152 us; speedup vs baseline: 1.1139x; 1.0358x over previous
//
#include <hip/hip_runtime.h>
#include <hip/hip_bf16.h>

#define B_    128
#define T_    1000
#define D_    1024
#define H_    256
#define TCROP 100
#define CHUNK 25
#define NCHK  40           // T_/CHUNK
#define CSKIP 4            // TCROP/CHUNK exact
#define NOUTC 36           // NCHK - CSKIP

typedef __attribute__((ext_vector_type(8))) short bfrag8;   // 8 x bf16
typedef __attribute__((ext_vector_type(4))) float f32x4;
typedef unsigned long long ull;

__device__ __forceinline__ float bf2f(unsigned short u) {
    union { unsigned int u; float f; } v; v.u = ((unsigned int)u) << 16;
    return v.f;
}
__device__ __forceinline__ unsigned short f2bf(float f) {
    union { float f; unsigned int u; } v; v.f = f;
    unsigned int u = v.u;
    u += 0x7FFFu + ((u >> 16) & 1u);
    return (unsigned short)(u >> 16);
}
// pack two f32 -> (bf16(hi)<<16)|bf16(lo), round-half-away: 2 adds + 1 v_perm
__device__ __forceinline__ unsigned int pack2(float lo, float hi) {
    union { float f; unsigned int u; } a, b; a.f = lo; b.f = hi;
    return __builtin_amdgcn_perm(b.u + 0x8000u, a.u + 0x8000u, 0x07060302u);
}
__device__ __forceinline__ bfrag8 cvt8(float4 f0, float4 f1) {
    union { bfrag8 v; unsigned int u[4]; } r;
    r.u[0] = pack2(f0.x, f0.y);
    r.u[1] = pack2(f0.z, f0.w);
    r.u[2] = pack2(f1.x, f1.y);
    r.u[3] = pack2(f1.z, f1.w);
    return r.v;
}

// ---------------------------------------------------------------------------
// Kernel 0: W f32 [H][D] -> bf16 (row-major)
// ---------------------------------------------------------------------------
__global__ __launch_bounds__(256) void wconv_kernel(
        const float* __restrict__ W, unsigned short* __restrict__ Wbf) {
    const int i = (blockIdx.x * 256 + threadIdx.x) * 8;
    float4 f0 = *(const float4*)(W + i);
    float4 f1 = *(const float4*)(W + i + 4);
    *(bfrag8*)(Wbf + i) = cvt8(f0, f1);
}

// ---------------------------------------------------------------------------
// Kernel 1: Wx = x . W^T  (bf16 MFMA, bf16 out). BM=128, BN=256(=H), BK=64.
// Round-2 proven core: single-buffer 48 KB LDS, 2 barriers/K-step, loads NOT
// live across MFMA (no cross-barrier prefetch -- rounds 3/4/5 showed it costs
// occupancy/spills). A f32 loads issued BEFORE B gload_lds so the cvt waits
// on vmcnt(4), keeping B in flight through the cvt+write.
// ---------------------------------------------------------------------------
__global__ __launch_bounds__(512) void gemm_kernel(
        const float* __restrict__ x, const unsigned short* __restrict__ Wbf,
        unsigned short* __restrict__ Wx) {
    __shared__ unsigned short As[128 * 64];   // 16 KB
    __shared__ unsigned short Bs[256 * 64];   // 32 KB

    const int tid  = threadIdx.x;
    const int lane = tid & 63;
    const int wave = tid >> 6;
    const int wr   = wave >> 2;
    const int wc   = wave & 3;
    const int m0   = blockIdx.x * 128;

    f32x4 acc[4][4];
#pragma unroll
    for (int m = 0; m < 4; ++m)
#pragma unroll
        for (int n = 0; n < 4; ++n) acc[m][n] = (f32x4){0.f, 0.f, 0.f, 0.f};

    const int rr  = lane & 15;
    const int kh  = lane >> 4;
    const int ra0 = tid >> 3;
    const int ja  = tid & 7;
    const int sa  = (ja ^ (ra0 & 7)) * 8;
    const float* ap0 = x + (size_t)(m0 + ra0) * D_ + ja * 8;
    const float* ap1 = ap0 + (size_t)64 * D_;

    for (int it = 0; it < 16; ++it) {
        const int kt = it * 64;
        // ---- A loads issued first (complete while B issues below) ----
        float4 f00 = *(const float4*)(ap0 + kt);
        float4 f01 = *(const float4*)(ap0 + kt + 4);
        float4 f10 = *(const float4*)(ap1 + kt);
        float4 f11 = *(const float4*)(ap1 + kt + 4);
        // ---- B stage: global_load_lds, source pre-swizzled ----
#pragma unroll
        for (int q = 0; q < 4; ++q) {
            const int li = q * 512 + tid;
            const int r = li >> 3, j = li & 7;
            const int jj = j ^ (r & 7);
            __builtin_amdgcn_global_load_lds(
                (const __attribute__((address_space(1))) void*)
                    (Wbf + (size_t)r * D_ + kt + jj * 8),
                (__attribute__((address_space(3))) void*)&Bs[li * 8], 16, 0, 0);
        }
        // ---- A: cvt + swizzled ds_write ----
        *(bfrag8*)&As[ra0 * 64 + sa]        = cvt8(f00, f01);
        *(bfrag8*)&As[(ra0 + 64) * 64 + sa] = cvt8(f10, f11);
        __syncthreads();
        // ---- MFMA ----
#pragma unroll
        for (int kk = 0; kk < 2; ++kk) {
            const int c16 = kk * 4 + kh;
            bfrag8 af[4], bfr[4];
#pragma unroll
            for (int m = 0; m < 4; ++m) {
                const int row = wr * 64 + m * 16 + rr;
                af[m] = *(const bfrag8*)&As[row * 64 + ((c16 ^ (row & 7)) * 8)];
            }
#pragma unroll
            for (int n = 0; n < 4; ++n) {
                const int row = wc * 64 + n * 16 + rr;
                bfr[n] = *(const bfrag8*)&Bs[row * 64 + ((c16 ^ (row & 7)) * 8)];
            }
#pragma unroll
            for (int m = 0; m < 4; ++m)
#pragma unroll
                for (int n = 0; n < 4; ++n)
                    acc[m][n] = __builtin_amdgcn_mfma_f32_16x16x32_bf16(
                        af[m], bfr[n], acc[m][n], 0, 0, 0);
        }
        __syncthreads();
    }

    const int cl = lane & 15, rg = lane >> 4;
#pragma unroll
    for (int m = 0; m < 4; ++m)
#pragma unroll
        for (int n = 0; n < 4; ++n)
#pragma unroll
            for (int j = 0; j < 4; ++j) {
                const int row = m0 + wr * 64 + m * 16 + rg * 4 + j;
                const int col = wc * 64 + n * 16 + cl;
                Wx[(size_t)row * H_ + col] = f2bf(acc[m][n][j]);
            }
}

// ---------------------------------------------------------------------------
// Kernel 2 (scanA): chunk-local zero-seeded EMA finals F. 4 waves/block,
// wave w owns chunk c = bx*4+w of batch b. Lane owns 4 h.
// ---------------------------------------------------------------------------
__global__ __launch_bounds__(256) void scanA_kernel(
        const unsigned short* __restrict__ Wx, const float* __restrict__ alpha,
        float* __restrict__ F) {
    const int wave = threadIdx.x >> 6;
    const int lane = threadIdx.x & 63;
    const int c = blockIdx.x * 4 + wave;      // 0..39
    const int b = blockIdx.y;
    const int h4 = lane * 4;

    const float AMIN = 0.81873075307798182f, AMAX = 0.96078943915232320f;
    float4 al = *(const float4*)(alpha + h4);
    float a[4]  = {fminf(fmaxf(al.x, AMIN), AMAX), fminf(fmaxf(al.y, AMIN), AMAX),
                   fminf(fmaxf(al.z, AMIN), AMAX), fminf(fmaxf(al.w, AMIN), AMAX)};
    float om[4] = {1.f - a[0], 1.f - a[1], 1.f - a[2], 1.f - a[3]};

    float ut[4] = {0.f, 0.f, 0.f, 0.f};
    const unsigned short* base = Wx + ((size_t)b * T_ + c * CHUNK) * H_ + h4;
#pragma unroll 5
    for (int t = 0; t < CHUNK; ++t) {
        ull wv = *(const ull*)(base + (size_t)t * H_);
        ut[0] = a[0] * ut[0] + om[0] * bf2f((unsigned short)wv);
        ut[1] = a[1] * ut[1] + om[1] * bf2f((unsigned short)(wv >> 16));
        ut[2] = a[2] * ut[2] + om[2] * bf2f((unsigned short)(wv >> 32));
        ut[3] = a[3] * ut[3] + om[3] * bf2f((unsigned short)(wv >> 48));
    }
    float4 o; o.x = ut[0]; o.y = ut[1]; o.z = ut[2]; o.w = ut[3];
    *(float4*)(F + ((size_t)b * NCHK + c) * H_ + h4) = o;
}

// ---------------------------------------------------------------------------
// Kernel 3 (scanC): seed-chain from F (a^25 powers, F is L2-hot), then
// seeded softmax accumulation over the chunk. Wave w owns chunk c=4+bx*4+w.
// 5-t batches -> 5 independent shfl-reduction trees.
// ---------------------------------------------------------------------------
__global__ __launch_bounds__(256) void scanC_kernel(
        const unsigned short* __restrict__ Wx, const float* __restrict__ alpha,
        const float* __restrict__ F, float* __restrict__ P) {
    const int wave = threadIdx.x >> 6;
    const int lane = threadIdx.x & 63;
    const int c = CSKIP + blockIdx.x * 4 + wave;   // 4..39
    const int b = blockIdx.y;
    const int h4 = lane * 4;

    const float AMIN = 0.81873075307798182f, AMAX = 0.96078943915232320f;
    float4 al = *(const float4*)(alpha + h4);
    float a[4]  = {fminf(fmaxf(al.x, AMIN), AMAX), fminf(fmaxf(al.y, AMIN), AMAX),
                   fminf(fmaxf(al.z, AMIN), AMAX), fminf(fmaxf(al.w, AMIN), AMAX)};
    float om[4] = {1.f - a[0], 1.f - a[1], 1.f - a[2], 1.f - a[3]};

    // carry chain: S = ut at chunk start
    float aL[4] = {__powf(a[0], (float)CHUNK), __powf(a[1], (float)CHUNK),
                   __powf(a[2], (float)CHUNK), __powf(a[3], (float)CHUNK)};
    float S[4] = {0.f, 0.f, 0.f, 0.f};
    for (int j = 0; j < c; ++j) {
        float4 f = *(const float4*)(F + ((size_t)b * NCHK + j) * H_ + h4);
        S[0] = aL[0] * S[0] + f.x;
        S[1] = aL[1] * S[1] + f.y;
        S[2] = aL[2] * S[2] + f.z;
        S[3] = aL[3] * S[3] + f.w;
    }

    float ut[4]   = {S[0], S[1], S[2], S[3]};
    float acc4[4] = {0.f, 0.f, 0.f, 0.f};
    const unsigned short* base = Wx + ((size_t)b * T_ + c * CHUNK) * H_ + h4;

#pragma unroll
    for (int bb = 0; bb < CHUNK; bb += 5) {
        float e[5][4], sl[5];
#pragma unroll
        for (int q = 0; q < 5; ++q) {
            ull wv = *(const ull*)(base + (size_t)(bb + q) * H_);
            ut[0] = a[0] * ut[0] + om[0] * bf2f((unsigned short)wv);
            ut[1] = a[1] * ut[1] + om[1] * bf2f((unsigned short)(wv >> 16));
            ut[2] = a[2] * ut[2] + om[2] * bf2f((unsigned short)(wv >> 32));
            ut[3] = a[3] * ut[3] + om[3] * bf2f((unsigned short)(wv >> 48));
            e[q][0] = __expf(ut[0]);   // |ut| small: no overflow, skip max-sub
            e[q][1] = __expf(ut[1]);
            e[q][2] = __expf(ut[2]);
            e[q][3] = __expf(ut[3]);
            sl[q] = (e[q][0] + e[q][1]) + (e[q][2] + e[q][3]);
        }
#pragma unroll
        for (int dd = 1; dd < 64; dd <<= 1) {
            sl[0] += __shfl_xor(sl[0], dd);
            sl[1] += __shfl_xor(sl[1], dd);
            sl[2] += __shfl_xor(sl[2], dd);
            sl[3] += __shfl_xor(sl[3], dd);
            sl[4] += __shfl_xor(sl[4], dd);
        }
#pragma unroll
        for (int q = 0; q < 5; ++q) {
            const float rcp = 1.0f / sl[q];
            acc4[0] += e[q][0] * rcp;
            acc4[1] += e[q][1] * rcp;
            acc4[2] += e[q][2] * rcp;
            acc4[3] += e[q][3] * rcp;
        }
    }
    float4 o; o.x = acc4[0]; o.y = acc4[1]; o.z = acc4[2]; o.w = acc4[3];
    *(float4*)(P + ((size_t)b * NOUTC + (c - CSKIP)) * H_ + h4) = o;
}

// ---------------------------------------------------------------------------
// Kernel 4: reduce chunk partials
// ---------------------------------------------------------------------------
__global__ __launch_bounds__(256) void scanD_kernel(
        const float* __restrict__ P, float* __restrict__ out) {
    const int b = blockIdx.x, h = threadIdx.x;
    float s = 0.f;
#pragma unroll 4
    for (int k = 0; k < NOUTC; ++k) s += P[((size_t)b * NOUTC + k) * H_ + h];
    out[(size_t)b * H_ + h] = s;
}

extern "C" void kernel_launch(void* const* d_in, const int* in_sizes, int n_in,
                              void* d_out, int out_size, void* d_ws, size_t ws_size,
                              hipStream_t stream) {
    const float* x     = (const float*)d_in[0];   // [B,T,D]
    const float* W     = (const float*)d_in[1];   // [H,D]
    const float* alpha = (const float*)d_in[2];   // [H]
    float* out = (float*)d_out;                   // [B,H]

    char* ws = (char*)d_ws;
    unsigned short* Wbf = (unsigned short*)ws;                        // 512 KB
    unsigned short* Wx  = (unsigned short*)(ws + ((size_t)1 << 20));  // 65.5 MB
    float* F = (float*)(ws + ((size_t)70 << 20));                     // 5.2 MB
    float* P = (float*)(ws + ((size_t)80 << 20));                     // 4.7 MB

    wconv_kernel<<<128, 256, 0, stream>>>(W, Wbf);
    gemm_kernel<<<(B_ * T_) / 128, 512, 0, stream>>>(x, Wbf, Wx);
    scanA_kernel<<<dim3(NCHK / 4, B_), 256, 0, stream>>>(Wx, alpha, F);
    scanC_kernel<<<dim3(NOUTC / 4, B_), 256, 0, stream>>>(Wx, alpha, F, P);
    scanD_kernel<<<B_, 256, 0, stream>>>(P, out);
}

// Round 7
// 187.296 us; speedup vs baseline: 1.1190x; 1.0046x over previous
//
#include <hip/hip_runtime.h>
#include <hip/hip_bf16.h>

#define B_    128
#define T_    1000
#define D_    1024
#define H_    256
#define TCROP 100
#define CHUNK 25
#define NCHK  40           // T_/CHUNK
#define CSKIP 4            // TCROP/CHUNK exact
#define NOUTC 36           // NCHK - CSKIP
#define BM    125          // valid rows per gemm block (chunk-aligned)

typedef __attribute__((ext_vector_type(8))) short bfrag8;   // 8 x bf16
typedef __attribute__((ext_vector_type(4))) float f32x4;
typedef unsigned long long ull;

__device__ __forceinline__ float bf2f(unsigned short u) {
    union { unsigned int u; float f; } v; v.u = ((unsigned int)u) << 16;
    return v.f;
}
__device__ __forceinline__ unsigned short f2bf(float f) {
    union { float f; unsigned int u; } v; v.f = f;
    unsigned int u = v.u;
    u += 0x7FFFu + ((u >> 16) & 1u);
    return (unsigned short)(u >> 16);
}
// pack two f32 -> (bf16(hi)<<16)|bf16(lo), round-half-away: 2 adds + 1 v_perm
__device__ __forceinline__ unsigned int pack2(float lo, float hi) {
    union { float f; unsigned int u; } a, b; a.f = lo; b.f = hi;
    return __builtin_amdgcn_perm(b.u + 0x8000u, a.u + 0x8000u, 0x07060302u);
}
__device__ __forceinline__ bfrag8 cvt8(float4 f0, float4 f1) {
    union { bfrag8 v; unsigned int u[4]; } r;
    r.u[0] = pack2(f0.x, f0.y);
    r.u[1] = pack2(f0.z, f0.w);
    r.u[2] = pack2(f1.x, f1.y);
    r.u[3] = pack2(f1.z, f1.w);
    return r.v;
}

// ---------------------------------------------------------------------------
// Kernel 0: W f32 [H][D] -> bf16 (row-major)
// ---------------------------------------------------------------------------
__global__ __launch_bounds__(256) void wconv_kernel(
        const float* __restrict__ W, unsigned short* __restrict__ Wbf) {
    const int i = (blockIdx.x * 256 + threadIdx.x) * 8;
    float4 f0 = *(const float4*)(W + i);
    float4 f1 = *(const float4*)(W + i + 4);
    *(bfrag8*)(Wbf + i) = cvt8(f0, f1);
}

// ---------------------------------------------------------------------------
// Kernel 1: block (c,b) computes Wx rows t=[c*125, c*125+125) of batch b
// (BM=125 valid rows, 3 pad rows clamped), K-loop identical to round 6.
// Epilogue: acc -> LDS C-tile (bf16, col-XOR swizzle), then
//   waves 0-3: serial EMA over 125 rows, snapshot every 25 -> F (kills scanA)
//   waves 4-7: coalesced b128 Wx stores from LDS, t>=100 only.
// LDS: union(staging 48KB, C-tile 62.5KB) = 64000 B -> 2 blocks/CU.
// ---------------------------------------------------------------------------
__global__ __launch_bounds__(512) void gemm_ema_kernel(
        const float* __restrict__ x, const unsigned short* __restrict__ Wbf,
        const float* __restrict__ alpha,
        unsigned short* __restrict__ Wx, float* __restrict__ F) {
    __shared__ unsigned short smem[32000];    // 64000 B
    unsigned short* As = smem;                // [128][64] bf16
    unsigned short* Bs = smem + 128 * 64;     // [256][64] bf16

    const int tid  = threadIdx.x;
    const int lane = tid & 63;
    const int wave = tid >> 6;
    const int wr   = wave >> 2;
    const int wc   = wave & 3;
    const int c    = blockIdx.x;         // 0..7
    const int b    = blockIdx.y;
    const int m0   = b * T_ + c * BM;    // rows 0..124 valid, same b

    f32x4 acc[4][4];
#pragma unroll
    for (int m = 0; m < 4; ++m)
#pragma unroll
        for (int n = 0; n < 4; ++n) acc[m][n] = (f32x4){0.f, 0.f, 0.f, 0.f};

    const int rr  = lane & 15;
    const int kh  = lane >> 4;
    const int ra0 = tid >> 3;
    const int ja  = tid & 7;
    const int sa  = (ja ^ (ra0 & 7)) * 8;
    const int r1  = (ra0 + 64 <= BM - 1) ? ra0 + 64 : BM - 1;   // clamp pad rows
    const float* ap0 = x + (size_t)(m0 + ra0) * D_ + ja * 8;
    const float* ap1 = x + (size_t)(m0 + r1) * D_ + ja * 8;

    for (int it = 0; it < 16; ++it) {
        const int kt = it * 64;
        // ---- A loads issued first (complete while B issues below) ----
        float4 f00 = *(const float4*)(ap0 + kt);
        float4 f01 = *(const float4*)(ap0 + kt + 4);
        float4 f10 = *(const float4*)(ap1 + kt);
        float4 f11 = *(const float4*)(ap1 + kt + 4);
        // ---- B stage: global_load_lds, source pre-swizzled ----
#pragma unroll
        for (int q = 0; q < 4; ++q) {
            const int li = q * 512 + tid;
            const int r = li >> 3, j = li & 7;
            const int jj = j ^ (r & 7);
            __builtin_amdgcn_global_load_lds(
                (const __attribute__((address_space(1))) void*)
                    (Wbf + (size_t)r * D_ + kt + jj * 8),
                (__attribute__((address_space(3))) void*)&Bs[li * 8], 16, 0, 0);
        }
        // ---- A: cvt + swizzled ds_write ----
        *(bfrag8*)&As[ra0 * 64 + sa]        = cvt8(f00, f01);
        *(bfrag8*)&As[(ra0 + 64) * 64 + sa] = cvt8(f10, f11);
        __syncthreads();
        // ---- MFMA ----
#pragma unroll
        for (int kk = 0; kk < 2; ++kk) {
            const int c16 = kk * 4 + kh;
            bfrag8 af[4], bfr[4];
#pragma unroll
            for (int m = 0; m < 4; ++m) {
                const int row = wr * 64 + m * 16 + rr;
                af[m] = *(const bfrag8*)&As[row * 64 + ((c16 ^ (row & 7)) * 8)];
            }
#pragma unroll
            for (int n = 0; n < 4; ++n) {
                const int row = wc * 64 + n * 16 + rr;
                bfr[n] = *(const bfrag8*)&Bs[row * 64 + ((c16 ^ (row & 7)) * 8)];
            }
#pragma unroll
            for (int m = 0; m < 4; ++m)
#pragma unroll
                for (int n = 0; n < 4; ++n)
                    acc[m][n] = __builtin_amdgcn_mfma_f32_16x16x32_bf16(
                        af[m], bfr[n], acc[m][n], 0, 0, 0);
        }
        __syncthreads();
    }

    // ---- acc -> LDS C-tile [125][256] bf16, col swizzle:
    //      scol = col ^ (((row>>2)&3)<<4)  (spreads the 4 rg-groups to
    //      disjoint bank sets on write; reads stay contiguous) ----
    const int cl = lane & 15, rg = lane >> 4;
#pragma unroll
    for (int m = 0; m < 4; ++m)
#pragma unroll
        for (int n = 0; n < 4; ++n)
#pragma unroll
            for (int j = 0; j < 4; ++j) {
                const int row = wr * 64 + m * 16 + rg * 4 + j;
                if (row < BM) {
                    const int col = wc * 64 + n * 16 + cl;
                    smem[row * 256 + (col ^ (((row >> 2) & 3) << 4))] =
                        f2bf(acc[m][n][j]);
                }
            }
    __syncthreads();

    if (tid < 256) {
        // ---- waves 0-3: chunk-local EMA, snapshot every 25 rows -> F ----
        const int h = tid;
        const float AMIN = 0.81873075307798182f, AMAX = 0.96078943915232320f;
        const float a  = fminf(fmaxf(alpha[h], AMIN), AMAX);
        const float om = 1.0f - a;
        float ut = 0.f;
        const size_t fbase = ((size_t)b * NCHK + c * 5) * H_ + h;
#pragma unroll 5
        for (int r = 0; r < BM; ++r) {
            ut = a * ut + om * bf2f(smem[r * 256 + (h ^ (((r >> 2) & 3) << 4))]);
            if ((r % 25) == 24) {
                F[fbase + (size_t)(r / 25) * H_] = ut;
                ut = 0.f;
            }
        }
    } else {
        // ---- waves 4-7: coalesced Wx stores from LDS (t>=100 only) ----
        const int nrows = (c == 0) ? (BM - TCROP) : BM;
        const int rbase = (c == 0) ? TCROP : 0;
        const int total = nrows * 32;             // 32 b128-slots per row
        for (int li = tid - 256; li < total; li += 256) {
            const int r  = rbase + (li >> 5);
            const int cg = (li & 31) * 8;
            const int scg = cg ^ (((r >> 2) & 3) << 4);
            bfrag8 v = *(const bfrag8*)&smem[r * 256 + scg];
            const int t = c * BM + r;
            *(bfrag8*)&Wx[((size_t)b * T_ + t) * H_ + cg] = v;
        }
    }
}

// ---------------------------------------------------------------------------
// Kernel 2 (scanC): seed-chain from F (a^25 powers, F is L2-hot), then
// seeded softmax accumulation over the chunk. Wave w owns chunk c=4+bx*4+w.
// ---------------------------------------------------------------------------
__global__ __launch_bounds__(256) void scanC_kernel(
        const unsigned short* __restrict__ Wx, const float* __restrict__ alpha,
        const float* __restrict__ F, float* __restrict__ P) {
    const int wave = threadIdx.x >> 6;
    const int lane = threadIdx.x & 63;
    const int c = CSKIP + blockIdx.x * 4 + wave;   // 4..39
    const int b = blockIdx.y;
    const int h4 = lane * 4;

    const float AMIN = 0.81873075307798182f, AMAX = 0.96078943915232320f;
    float4 al = *(const float4*)(alpha + h4);
    float a[4]  = {fminf(fmaxf(al.x, AMIN), AMAX), fminf(fmaxf(al.y, AMIN), AMAX),
                   fminf(fmaxf(al.z, AMIN), AMAX), fminf(fmaxf(al.w, AMIN), AMAX)};
    float om[4] = {1.f - a[0], 1.f - a[1], 1.f - a[2], 1.f - a[3]};

    // carry chain: S = ut at chunk start
    float aL[4] = {__powf(a[0], (float)CHUNK), __powf(a[1], (float)CHUNK),
                   __powf(a[2], (float)CHUNK), __powf(a[3], (float)CHUNK)};
    float S[4] = {0.f, 0.f, 0.f, 0.f};
    for (int j = 0; j < c; ++j) {
        float4 f = *(const float4*)(F + ((size_t)b * NCHK + j) * H_ + h4);
        S[0] = aL[0] * S[0] + f.x;
        S[1] = aL[1] * S[1] + f.y;
        S[2] = aL[2] * S[2] + f.z;
        S[3] = aL[3] * S[3] + f.w;
    }

    float ut[4]   = {S[0], S[1], S[2], S[3]};
    float acc4[4] = {0.f, 0.f, 0.f, 0.f};
    const unsigned short* base = Wx + ((size_t)b * T_ + c * CHUNK) * H_ + h4;

#pragma unroll
    for (int bb = 0; bb < CHUNK; bb += 5) {
        float e[5][4], sl[5];
#pragma unroll
        for (int q = 0; q < 5; ++q) {
            ull wv = *(const ull*)(base + (size_t)(bb + q) * H_);
            ut[0] = a[0] * ut[0] + om[0] * bf2f((unsigned short)wv);
            ut[1] = a[1] * ut[1] + om[1] * bf2f((unsigned short)(wv >> 16));
            ut[2] = a[2] * ut[2] + om[2] * bf2f((unsigned short)(wv >> 32));
            ut[3] = a[3] * ut[3] + om[3] * bf2f((unsigned short)(wv >> 48));
            e[q][0] = __expf(ut[0]);   // |ut| small: no overflow, skip max-sub
            e[q][1] = __expf(ut[1]);
            e[q][2] = __expf(ut[2]);
            e[q][3] = __expf(ut[3]);
            sl[q] = (e[q][0] + e[q][1]) + (e[q][2] + e[q][3]);
        }
#pragma unroll
        for (int dd = 1; dd < 64; dd <<= 1) {
            sl[0] += __shfl_xor(sl[0], dd);
            sl[1] += __shfl_xor(sl[1], dd);
            sl[2] += __shfl_xor(sl[2], dd);
            sl[3] += __shfl_xor(sl[3], dd);
            sl[4] += __shfl_xor(sl[4], dd);
        }
#pragma unroll
        for (int q = 0; q < 5; ++q) {
            const float rcp = 1.0f / sl[q];
            acc4[0] += e[q][0] * rcp;
            acc4[1] += e[q][1] * rcp;
            acc4[2] += e[q][2] * rcp;
            acc4[3] += e[q][3] * rcp;
        }
    }
    float4 o; o.x = acc4[0]; o.y = acc4[1]; o.z = acc4[2]; o.w = acc4[3];
    *(float4*)(P + ((size_t)b * NOUTC + (c - CSKIP)) * H_ + h4) = o;
}

// ---------------------------------------------------------------------------
// Kernel 3: reduce chunk partials
// ---------------------------------------------------------------------------
__global__ __launch_bounds__(256) void scanD_kernel(
        const float* __restrict__ P, float* __restrict__ out) {
    const int b = blockIdx.x, h = threadIdx.x;
    float s = 0.f;
#pragma unroll 4
    for (int k = 0; k < NOUTC; ++k) s += P[((size_t)b * NOUTC + k) * H_ + h];
    out[(size_t)b * H_ + h] = s;
}

extern "C" void kernel_launch(void* const* d_in, const int* in_sizes, int n_in,
                              void* d_out, int out_size, void* d_ws, size_t ws_size,
                              hipStream_t stream) {
    const float* x     = (const float*)d_in[0];   // [B,T,D]
    const float* W     = (const float*)d_in[1];   // [H,D]
    const float* alpha = (const float*)d_in[2];   // [H]
    float* out = (float*)d_out;                   // [B,H]

    char* ws = (char*)d_ws;
    unsigned short* Wbf = (unsigned short*)ws;                        // 512 KB
    unsigned short* Wx  = (unsigned short*)(ws + ((size_t)1 << 20));  // 65.5 MB
    float* F = (float*)(ws + ((size_t)70 << 20));                     // 5.2 MB
    float* P = (float*)(ws + ((size_t)80 << 20));                     // 4.7 MB

    wconv_kernel<<<128, 256, 0, stream>>>(W, Wbf);
    gemm_ema_kernel<<<dim3(T_ / BM, B_), 512, 0, stream>>>(x, Wbf, alpha, Wx, F);
    scanC_kernel<<<dim3(NOUTC / 4, B_), 256, 0, stream>>>(Wx, alpha, F, P);
    scanD_kernel<<<B_, 256, 0, stream>>>(P, out);
}